// Round 4
// baseline (330.857 us; speedup 1.0000x reference)
//
#include <hip/hip_runtime.h>
#include <hip/hip_fp8.h>
#include <math.h>

#define N_ROWS 16384
#define M_ROWS 16384
#define DIM    512
#define JS     8        // j-splits in pass1 (one per XCD)
#define KCAND  256      // max rescore candidates
#define DELTA  0.40f    // selection margin (fp8 dist err sigma ~0.03 -> 13 sigma)

typedef __attribute__((ext_vector_type(8))) int   int8v;
typedef __attribute__((ext_vector_type(4))) int   int4v;
typedef __attribute__((ext_vector_type(4))) float floatx4;

// ---------------- 1. convert fp32 -> fp8 e4m3, exact row norms, init control ----------------
__global__ __launch_bounds__(256) void convert_kernel(const float* __restrict__ x, const float* __restrict__ y,
                                                      unsigned char* __restrict__ xh8, unsigned char* __restrict__ yh8,
                                                      float* __restrict__ x_sq, float* __restrict__ y_sq,
                                                      unsigned int* __restrict__ gmax_bits,
                                                      unsigned int* __restrict__ cnt, int* __restrict__ cand) {
    if (blockIdx.x == 0) {
        if (threadIdx.x < KCAND) cand[threadIdx.x] = 0;
        if (threadIdx.x == 0) { *gmax_bits = 0u; *cnt = 0u; }
    }
    int wave = threadIdx.x >> 6, lane = threadIdx.x & 63;
    int row = blockIdx.x * 4 + wave;
    const float* src; unsigned char* dst8; float* dsq; int r;
    if (row < N_ROWS) { r = row;          src = x; dst8 = xh8; dsq = x_sq; }
    else              { r = row - N_ROWS; src = y; dst8 = yh8; dsq = y_sq; }
    const float4* s4 = (const float4*)(src + (size_t)r * DIM);
    float4 a = s4[lane * 2];
    float4 b = s4[lane * 2 + 1];
    float v[8] = {a.x, a.y, a.z, a.w, b.x, b.y, b.z, b.w};
    union { unsigned char b[8]; uint2 u2; } pk;
    float s = 0.f;
    #pragma unroll
    for (int i = 0; i < 8; ++i) {
        s += v[i] * v[i];
        __hip_fp8_e4m3 q(v[i]);
        pk.b[i] = (unsigned char)q.__x;
    }
    *(uint2*)(dst8 + (size_t)r * DIM + lane * 8) = pk.u2;
    #pragma unroll
    for (int off = 32; off > 0; off >>= 1) s += __shfl_down(s, off, 64);
    if (lane == 0) dsq[r] = s;
}

// ---------------- 2. pass1: MX-fp8 MFMA (unit scales), min_j(y_sq[j] - 2 x.y) ----------------
// 256 threads / 4 waves, 1 block/CU (regs + LDS both cap there). Wave (h,c) owns a 64-row x
// 64-col quadrant: afr[4][4] (128 VGPR, resident at 1 wave/SIMD = 512-reg budget) via the
// proven LDS round-trip; B staging is WAVE-PRIVATE (each wave DMAs its own 64 cols x 128 kB
// into private 4-buffer LDS) -> consumer==producer -> ZERO barriers in the main loop, exact
// per-wave s_waitcnt vmcnt(16) depth-2 pipeline. phi-swizzled layout (conflict-free b128).
__global__ __launch_bounds__(256, 1) void pass1_kernel(const unsigned char* __restrict__ xh8,
                                                       const unsigned char* __restrict__ yh8,
                                                       const float* __restrict__ y_sq,
                                                       float* __restrict__ part) {
    __shared__ __align__(16) unsigned char Bs[4][32768];   // per-wave: 4 bufs x 8 KB
    __shared__ __align__(16) float ysq_s[M_ROWS / JS];     // this block's y_sq slice (8 KB)
    __shared__ float red[2][128];

    const int t = threadIdx.x;
    const int w = t >> 6, lane = t & 63;
    const int col = lane & 15, q = lane >> 4;
    const int h = w >> 1, c = w & 1;        // row-half, col-half

    // XCD swizzle (1024 blocks % 8 == 0): XCD x owns jsplit x -> its 1MB y-slice stays in L2
    const int bid = blockIdx.x;
    const int wg = (bid & 7) * 128 + (bid >> 3);
    const int js = wg >> 7;                 // 0..7
    const int i0 = (wg & 127) * 128;        // x-row base
    const int jbase = js * (M_ROWS / JS);

    // ---- prologue: y_sq slice -> LDS ----
    {
        const float4* ys4 = (const float4*)(y_sq + jbase);
        float4 v0 = ys4[t * 2];
        float4 v1 = ys4[t * 2 + 1];
        *(float4*)&ysq_s[t * 8]     = v0;
        *(float4*)&ysq_s[t * 8 + 4] = v1;
    }

    // ---- A tile (128 rows x 512 B) -> Bs (first 64 KB) with phi-chunk swizzle ----
    // physical 16B slot (r, kq, p) holds logical chunk cl = p ^ (r&7) of row r's kq-th 128B
    {
        const unsigned char* gs = xh8 + (size_t)i0 * DIM;
        unsigned char* ls = (unsigned char*)Bs;
        #pragma unroll
        for (int it = 0; it < 16; ++it) {
            int s  = it * 256 + t;          // 16B slot 0..4095
            int r  = s >> 5;                // A row 0..127
            int u  = s & 31;
            int kq = u >> 3;                // 128B k-chunk 0..3
            int cl = (u & 7) ^ (r & 7);     // logical chunk for this physical slot
            __builtin_amdgcn_global_load_lds(
                (const __attribute__((address_space(1))) void*)(gs + r * 512 + kq * 128 + cl * 16),
                (__attribute__((address_space(3))) void*)(ls + it * 4096 + w * 1024),
                16, 0, 0);
        }
    }
    __syncthreads();   // A staged (drains vmcnt), ysq_s visible

    // ---- A fragments -> registers: wave holds rows i0 + h*64 .. +63, all K (16 frags) ----
    // f8f6f4 16x16x128 A-layout: lane(q,col) holds row=col, k bytes [q*32, q*32+32)
    int8v afr[4][4];
    {
        const unsigned char* ab = (const unsigned char*)Bs;
        #pragma unroll
        for (int mt = 0; mt < 4; ++mt) {
            int rr = h * 64 + mt * 16 + col;
            #pragma unroll
            for (int kc = 0; kc < 4; ++kc) {
                int base = rr * 512 + kc * 128 + (((q << 1) ^ (rr & 7)) << 4);
                int4v a0 = *(const int4v*)(ab + base);
                int4v a1 = *(const int4v*)(ab + (base ^ 16));
                int8v f;
                f[0] = a0[0]; f[1] = a0[1]; f[2] = a0[2]; f[3] = a0[3];
                f[4] = a1[0]; f[5] = a1[1]; f[6] = a1[2]; f[7] = a1[3];
                afr[mt][kc] = f;
            }
        }
    }
    __syncthreads();   // all afr reads done before B pipeline overwrites Bs

    // ---- wave-private B staging offsets (phi-layout per 2KB group of 16 j-rows) ----
    // wave (h,c) stages cols [c*64, c*64+64) x 128 kB = 8 KB = 8 instrs/step, private bufs.
    int spo[8];
    {
        #pragma unroll
        for (int i = 0; i < 8; ++i) {
            int s  = i * 64 + lane;             // 16B slot in this wave's 8 KB
            int g  = s >> 7, u = s & 127;       // 2KB group 0..3, slot within
            int jl = c * 64 + (g << 4) + (u & 15);
            int p  = (u >> 4) ^ (u & 7);
            spo[i] = jl * DIM + p * 16;
        }
    }
    const unsigned char* tb = yh8 + (size_t)jbase * DIM;
    unsigned char* mybs = &Bs[w][0];
    const int Klane = col * 16 + (((q << 1) ^ (col & 7)) << 8);

    float minv[16];
    #pragma unroll
    for (int i = 0; i < 16; ++i) minv[i] = __builtin_inff();

#define STAGE(BUF, TOFF)                                                                     \
    { _Pragma("unroll")                                                                      \
      for (int i_ = 0; i_ < 8; ++i_) {                                                       \
          __builtin_amdgcn_global_load_lds(                                                  \
              (const __attribute__((address_space(1))) void*)(tb + spo[i_] + (TOFF)),        \
              (__attribute__((address_space(3))) void*)(mybs + (BUF) * 8192 + i_ * 1024),    \
              16, 0, 0);                                                                     \
      } }

    STAGE(0, 0)       // step 0: jt 0, kcol 0
    STAGE(1, 128)     // step 1: jt 0, kcol 128

    for (int jt = 0; jt < 16; ++jt) {
        floatx4 acc[4][4];
        #pragma unroll
        for (int mt = 0; mt < 4; ++mt)
            #pragma unroll
            for (int nt = 0; nt < 4; ++nt) acc[mt][nt] = (floatx4){0.f, 0.f, 0.f, 0.f};
        #pragma unroll
        for (int kc = 0; kc < 4; ++kc) {
            // stage step s+2 into buffer (kc+2)&3. Tail (jt=15, kc>=2) wraps jt' to 0:
            // stages junk into never-read buffers from L2-HOT addresses (no HBM junk fetch).
            const int jtp  = (jt + (kc >> 1)) & 15;
            const int toff = jtp * (128 * DIM) + (((kc + 2) & 3) << 7);
            STAGE((kc + 2) & 3, toff)
            // wave-private wait: 2 newer steps x 8 loads may remain in flight
            asm volatile("s_waitcnt vmcnt(16)" ::: "memory");
            #pragma unroll
            for (int nt = 0; nt < 4; ++nt) {
                const unsigned char* gb = mybs + kc * 8192 + nt * 2048;
                int4v lo = *(const int4v*)(gb + Klane);
                int4v hi = *(const int4v*)(gb + (Klane ^ 256));
                int8v b;
                b[0] = lo[0]; b[1] = lo[1]; b[2] = lo[2]; b[3] = lo[3];
                b[4] = hi[0]; b[5] = hi[1]; b[6] = hi[2]; b[7] = hi[3];
                __builtin_amdgcn_s_setprio(1);
                #pragma unroll
                for (int mt = 0; mt < 4; ++mt)
                    acc[mt][nt] = __builtin_amdgcn_mfma_scale_f32_16x16x128_f8f6f4(
                        afr[mt][kc], b, acc[mt][nt], 0, 0, 0, 127, 0, 127);
                __builtin_amdgcn_s_setprio(0);
            }
        }
        // fold y_sq (from LDS), running min over j (x_sq added later; sqrt monotone)
        #pragma unroll
        for (int nt = 0; nt < 4; ++nt) {
            float qv = ysq_s[jt * 128 + c * 64 + nt * 16 + col];
            #pragma unroll
            for (int mt = 0; mt < 4; ++mt)
                #pragma unroll
                for (int r = 0; r < 4; ++r)
                    minv[mt * 4 + r] = fminf(minv[mt * 4 + r], qv - 2.f * acc[mt][nt][r]);
        }
    }
#undef STAGE

    asm volatile("s_waitcnt vmcnt(0)" ::: "memory");   // drain tail junk stages

    // reduce over the 16 col-lanes (C-layout: col = lane&15, row = q*4+r)
    #pragma unroll
    for (int i = 0; i < 16; ++i) {
        float v = minv[i];
        v = fminf(v, __shfl_xor(v, 1, 64));
        v = fminf(v, __shfl_xor(v, 2, 64));
        v = fminf(v, __shfl_xor(v, 4, 64));
        v = fminf(v, __shfl_xor(v, 8, 64));
        minv[i] = v;
    }
    if (col == 0) {
        #pragma unroll
        for (int mt = 0; mt < 4; ++mt)
            #pragma unroll
            for (int r = 0; r < 4; ++r)
                red[c][h * 64 + mt * 16 + q * 4 + r] = minv[mt * 4 + r];
    }
    __syncthreads();
    if (t < 128)
        part[(size_t)(i0 + t) * JS + js] = fminf(red[0][t], red[1][t]);
}

// ---------------- 3a. per-row approx value + global max ----------------
__global__ __launch_bounds__(1024) void maxred_kernel(const float* __restrict__ part,
                                                      const float* __restrict__ x_sq,
                                                      float* __restrict__ aval,
                                                      unsigned int* __restrict__ gmax_bits) {
    __shared__ float sm[1024];
    int t = threadIdx.x;
    int row = blockIdx.x * 1024 + t;
    float m = part[(size_t)row * JS];
    #pragma unroll
    for (int c = 1; c < JS; ++c) m = fminf(m, part[(size_t)row * JS + c]);
    float v = sqrtf(fmaxf(x_sq[row] + m, 0.f));
    aval[row] = v;
    sm[t] = v;
    __syncthreads();
    for (int s = 512; s > 0; s >>= 1) {
        if (t < s) sm[t] = fmaxf(sm[t], sm[t + s]);
        __syncthreads();
    }
    if (t == 0) atomicMax(gmax_bits, __float_as_uint(sm[0]));  // v>=0: uint order == float order
}

// ---------------- 3b. select candidates within DELTA of max ----------------
__global__ __launch_bounds__(1024) void select_kernel(const float* __restrict__ aval,
                                                      const unsigned int* __restrict__ gmax_bits,
                                                      unsigned int* __restrict__ cnt,
                                                      int* __restrict__ cand) {
    int row = blockIdx.x * 1024 + threadIdx.x;
    float gmax = __uint_as_float(*gmax_bits);
    if (aval[row] >= gmax - DELTA) {
        unsigned s = atomicAdd(cnt, 1u);
        if (s < KCAND) cand[s] = row;
    }
}

// ---------------- 4. exact fp32 rescore of candidates vs all centers ----------------
#define TIr 64
#define LDA 68
#define LDB 132
__global__ __launch_bounds__(256) void rescore_kernel(const float* __restrict__ x, const float* __restrict__ y,
                                                      const float* __restrict__ y_sq,
                                                      const int* __restrict__ cand,
                                                      const unsigned int* __restrict__ cnt,
                                                      float* __restrict__ part2) {
    __shared__ __align__(16) float As[32 * LDA];
    __shared__ __align__(16) float Bs[32 * LDB];
    __shared__ float red[TIr][17];

    int t = threadIdx.x;
    int tx = t & 15, ty = t >> 4;
    int i0 = blockIdx.x * TIr;       // candidate slot base
    int j0 = blockIdx.y * 128;       // center base

    if ((unsigned)i0 >= *cnt) return;   // uniform early-exit: unused candidate blocks

    float acc[4][8];
    #pragma unroll
    for (int c = 0; c < 4; ++c)
        #pragma unroll
        for (int d = 0; d < 8; ++d) acc[c][d] = 0.f;

    int srow = t >> 3;
    int skq = (t & 7) * 4;
    int grow0 = cand[i0 + srow];
    int grow1 = cand[i0 + 32 + srow];

    for (int kc = 0; kc < DIM; kc += 32) {
        {
            float4 v = *(const float4*)(x + (size_t)grow0 * DIM + kc + skq);
            As[(skq + 0) * LDA + srow] = v.x;
            As[(skq + 1) * LDA + srow] = v.y;
            As[(skq + 2) * LDA + srow] = v.z;
            As[(skq + 3) * LDA + srow] = v.w;
            v = *(const float4*)(x + (size_t)grow1 * DIM + kc + skq);
            As[(skq + 0) * LDA + 32 + srow] = v.x;
            As[(skq + 1) * LDA + 32 + srow] = v.y;
            As[(skq + 2) * LDA + 32 + srow] = v.z;
            As[(skq + 3) * LDA + 32 + srow] = v.w;
        }
        #pragma unroll
        for (int it = 0; it < 4; ++it) {
            int row = it * 32 + srow;
            float4 v = *(const float4*)(y + (size_t)(j0 + row) * DIM + kc + skq);
            Bs[(skq + 0) * LDB + row] = v.x;
            Bs[(skq + 1) * LDB + row] = v.y;
            Bs[(skq + 2) * LDB + row] = v.z;
            Bs[(skq + 3) * LDB + row] = v.w;
        }
        __syncthreads();
        #pragma unroll 8
        for (int k = 0; k < 32; ++k) {
            float4 a  = *(const float4*)&As[k * LDA + ty * 4];
            float4 b0 = *(const float4*)&Bs[k * LDB + tx * 8];
            float4 b1 = *(const float4*)&Bs[k * LDB + tx * 8 + 4];
            float av[4] = {a.x, a.y, a.z, a.w};
            float bv[8] = {b0.x, b0.y, b0.z, b0.w, b1.x, b1.y, b1.z, b1.w};
            #pragma unroll
            for (int c = 0; c < 4; ++c)
                #pragma unroll
                for (int d = 0; d < 8; ++d)
                    acc[c][d] = fmaf(av[c], bv[d], acc[c][d]);
        }
        __syncthreads();
    }

    float4 q0 = *(const float4*)(y_sq + j0 + tx * 8);
    float4 q1 = *(const float4*)(y_sq + j0 + tx * 8 + 4);
    float qv[8] = {q0.x, q0.y, q0.z, q0.w, q1.x, q1.y, q1.z, q1.w};
    float mv[4] = {__builtin_inff(), __builtin_inff(), __builtin_inff(), __builtin_inff()};
    #pragma unroll
    for (int c = 0; c < 4; ++c)
        #pragma unroll
        for (int d = 0; d < 8; ++d)
            mv[c] = fminf(mv[c], qv[d] - 2.f * acc[c][d]);
    #pragma unroll
    for (int c = 0; c < 4; ++c) red[ty * 4 + c][tx] = mv[c];
    __syncthreads();
    if (t < TIr) {
        float m = red[t][0];
        #pragma unroll
        for (int xx = 1; xx < 16; ++xx) m = fminf(m, red[t][xx]);
        part2[(size_t)(i0 + t) * 128 + blockIdx.y] = m;
    }
}

// ---------------- 5. final: exact min per candidate, argmax with index tie-break ----------------
__global__ __launch_bounds__(256) void final2_kernel(const float* __restrict__ part2,
                                                     const float* __restrict__ x_sq,
                                                     const int* __restrict__ cand,
                                                     const unsigned int* __restrict__ cnt,
                                                     float* __restrict__ out) {
    __shared__ float sv[256];
    __shared__ int si[256];
    int t = threadIdx.x;
    const float4* p4 = (const float4*)(part2 + (size_t)t * 128);
    float m = __builtin_inff();
    for (int c = 0; c < 32; ++c) {
        float4 v = p4[c];
        m = fminf(m, fminf(fminf(v.x, v.y), fminf(v.z, v.w)));
    }
    unsigned n = *cnt;
    if (n > KCAND) n = KCAND;
    int row = cand[t];
    float v = (t < (int)n) ? sqrtf(fmaxf(x_sq[row] + m, 0.f)) : -__builtin_inff();
    sv[t] = v; si[t] = row;
    __syncthreads();
    for (int s = 128; s > 0; s >>= 1) {
        if (t < s) {
            float v2 = sv[t + s]; int i2 = si[t + s];
            if (v2 > sv[t] || (v2 == sv[t] && i2 < si[t])) { sv[t] = v2; si[t] = i2; }
        }
        __syncthreads();
    }
    if (t == 0) { out[0] = sv[0]; out[1] = (float)si[0]; }
}

extern "C" void kernel_launch(void* const* d_in, const int* in_sizes, int n_in,
                              void* d_out, int out_size, void* d_ws, size_t ws_size,
                              hipStream_t stream) {
    const float* x = (const float*)d_in[0];
    const float* y = (const float*)d_in[1];
    float* out = (float*)d_out;

    char* w = (char*)d_ws;
    unsigned char* xh8 = (unsigned char*)w;                           // 8 MB
    unsigned char* yh8 = (unsigned char*)(w + (size_t)8388608);       // 8 MB
    float* x_sq = (float*)(w + (size_t)16777216);                     // N
    float* y_sq = x_sq + N_ROWS;                                      // M
    float* part = y_sq + M_ROWS;                                      // N*JS
    float* aval = part + (size_t)N_ROWS * JS;                         // N
    float* part2 = aval + N_ROWS;                                     // KCAND*128
    int* cand = (int*)(part2 + KCAND * 128);                          // KCAND
    unsigned int* gmax_bits = (unsigned int*)(cand + KCAND);
    unsigned int* cnt = gmax_bits + 1;

    convert_kernel<<<(N_ROWS + M_ROWS) / 4, 256, 0, stream>>>(x, y, xh8, yh8, x_sq, y_sq, gmax_bits, cnt, cand);
    pass1_kernel<<<1024, 256, 0, stream>>>(xh8, yh8, y_sq, part);
    maxred_kernel<<<N_ROWS / 1024, 1024, 0, stream>>>(part, x_sq, aval, gmax_bits);
    select_kernel<<<N_ROWS / 1024, 1024, 0, stream>>>(aval, gmax_bits, cnt, cand);
    dim3 g2(KCAND / TIr, M_ROWS / 128);
    rescore_kernel<<<g2, 256, 0, stream>>>(x, y, y_sq, cand, cnt, part2);
    final2_kernel<<<1, 256, 0, stream>>>(part2, x_sq, cand, cnt, out);
}

// Round 5
// 293.030 us; speedup vs baseline: 1.1291x; 1.1291x over previous
//
#include <hip/hip_runtime.h>
#include <hip/hip_fp8.h>
#include <math.h>

#define N_ROWS 16384
#define M_ROWS 16384
#define DIM    512
#define JS     8        // j-splits in pass1 (one per XCD)
#define KCAND  256      // max rescore candidates
#define DELTA  0.40f    // selection margin (fp8 dist err sigma ~0.03 -> 13 sigma)

typedef __attribute__((ext_vector_type(8))) int   int8v;
typedef __attribute__((ext_vector_type(4))) int   int4v;
typedef __attribute__((ext_vector_type(4))) float floatx4;

// ---------------- 1. convert fp32 -> fp8 e4m3, exact row norms, init control ----------------
__global__ __launch_bounds__(256) void convert_kernel(const float* __restrict__ x, const float* __restrict__ y,
                                                      unsigned char* __restrict__ xh8, unsigned char* __restrict__ yh8,
                                                      float* __restrict__ x_sq, float* __restrict__ y_sq,
                                                      unsigned int* __restrict__ gmax_bits,
                                                      unsigned int* __restrict__ cnt, int* __restrict__ cand) {
    if (blockIdx.x == 0) {
        if (threadIdx.x < KCAND) cand[threadIdx.x] = 0;
        if (threadIdx.x == 0) { *gmax_bits = 0u; *cnt = 0u; }
    }
    int wave = threadIdx.x >> 6, lane = threadIdx.x & 63;
    int row = blockIdx.x * 4 + wave;
    const float* src; unsigned char* dst8; float* dsq; int r;
    if (row < N_ROWS) { r = row;          src = x; dst8 = xh8; dsq = x_sq; }
    else              { r = row - N_ROWS; src = y; dst8 = yh8; dsq = y_sq; }
    const float4* s4 = (const float4*)(src + (size_t)r * DIM);
    float4 a = s4[lane * 2];
    float4 b = s4[lane * 2 + 1];
    float v[8] = {a.x, a.y, a.z, a.w, b.x, b.y, b.z, b.w};
    union { unsigned char b[8]; uint2 u2; } pk;
    float s = 0.f;
    #pragma unroll
    for (int i = 0; i < 8; ++i) {
        s += v[i] * v[i];
        __hip_fp8_e4m3 q(v[i]);
        pk.b[i] = (unsigned char)q.__x;
    }
    *(uint2*)(dst8 + (size_t)r * DIM + lane * 8) = pk.u2;
    #pragma unroll
    for (int off = 32; off > 0; off >>= 1) s += __shfl_down(s, off, 64);
    if (lane == 0) dsq[r] = s;
}

// ---------------- 2. pass1: MX-fp8 MFMA (unit scales), min_j(y_sq[j] - 2 x.y) ----------------
// 512 threads / 8 waves, LDS=141KB forces 1 block/CU -> 2 waves/SIMD (latency hiding) with
// the full 256-reg/wave budget. Wave (h,c): h in {0,1} owns 64 rows (afr[4][4] = 128 VGPR,
// register-resident via LDS round-trip), c in {0..3} reads ONLY its 32 B-cols (2 frags/step).
// Per block-step LDS = 32KB reads + 16KB writes ~= 500 cyc vs MFMA 553 cyc/SIMD -> MFMA-bound.
// Shared cooperative B staging: 8 x 16KB buffers, depth-3 prefetch, ONE s_barrier + counted
// vmcnt(6) per step (never drained in-loop). phi-swizzled layout (conflict-free b128 reads).
__global__ __launch_bounds__(512, 1) void pass1_kernel(const unsigned char* __restrict__ xh8,
                                                       const unsigned char* __restrict__ yh8,
                                                       const float* __restrict__ y_sq,
                                                       float* __restrict__ part) {
    __shared__ __align__(16) unsigned char Bs[8][16384];   // 8 bufs x (128 j x 128 kB)
    __shared__ __align__(16) float ysq_s[M_ROWS / JS];     // this block's y_sq slice (8 KB)
    __shared__ float red[4][128];

    const int t = threadIdx.x;
    const int w = t >> 6, lane = t & 63;
    const int col = lane & 15, q = lane >> 4;
    const int h = w >> 2, c = w & 3;        // row-half (64 rows), col-quarter (32 cols)

    // XCD swizzle (1024 blocks % 8 == 0): XCD x owns jsplit x -> its 1MB y-slice stays in L2
    const int bid = blockIdx.x;
    const int wg = (bid & 7) * 128 + (bid >> 3);
    const int js = wg >> 7;                 // 0..7
    const int i0 = (wg & 127) * 128;        // x-row base
    const int jbase = js * (M_ROWS / JS);

    // ---- prologue: y_sq slice -> LDS ----
    {
        const float4* ys4 = (const float4*)(y_sq + jbase);
        *(float4*)&ysq_s[t * 4] = ys4[t];
    }

    // ---- A tile (128 rows x 512 B) -> Bs (first 64 KB) with phi-chunk swizzle ----
    // physical 16B slot (r, kq, p) holds logical chunk cl = p ^ (r&7) of row r's kq-th 128B
    {
        const unsigned char* gs = xh8 + (size_t)i0 * DIM;
        unsigned char* ls = (unsigned char*)Bs;
        #pragma unroll
        for (int it = 0; it < 8; ++it) {
            int s  = it * 512 + t;          // 16B slot 0..4095
            int r  = s >> 5;                // A row 0..127
            int u  = s & 31;
            int kq = u >> 3;                // 128B k-chunk 0..3
            int cl = (u & 7) ^ (r & 7);     // logical chunk for this physical slot
            __builtin_amdgcn_global_load_lds(
                (const __attribute__((address_space(1))) void*)(gs + r * 512 + kq * 128 + cl * 16),
                (__attribute__((address_space(3))) void*)(ls + it * 8192 + w * 1024),
                16, 0, 0);
        }
    }
    __syncthreads();   // A staged (drains vmcnt), ysq_s visible

    // ---- A fragments -> registers: wave holds rows i0 + h*64 .. +63, all K (16 frags) ----
    // f8f6f4 16x16x128 A-layout: lane(q,col) holds row=col, k bytes [q*32, q*32+32)
    int8v afr[4][4];
    {
        const unsigned char* ab = (const unsigned char*)Bs;
        #pragma unroll
        for (int mt = 0; mt < 4; ++mt) {
            int rr = h * 64 + mt * 16 + col;
            #pragma unroll
            for (int kc = 0; kc < 4; ++kc) {
                int base = rr * 512 + kc * 128 + (((q << 1) ^ (rr & 7)) << 4);
                int4v a0 = *(const int4v*)(ab + base);
                int4v a1 = *(const int4v*)(ab + (base ^ 16));
                int8v f;
                f[0] = a0[0]; f[1] = a0[1]; f[2] = a0[2]; f[3] = a0[3];
                f[4] = a1[0]; f[5] = a1[1]; f[6] = a1[2]; f[7] = a1[3];
                afr[mt][kc] = f;
            }
        }
    }
    __syncthreads();   // all afr reads done before B pipeline overwrites Bs

    // ---- shared B staging offsets (phi-layout: slot u = j4 + 16*(p ^ (j4&7)) per 2KB group) ----
    // 512 threads x 2 slots cover the 16 KB step tile (128 cols x 128 kB).
    int spo[2];
    {
        #pragma unroll
        for (int i = 0; i < 2; ++i) {
            int s  = i * 512 + t;               // 16B slot this thread fills
            int g  = s >> 7, u = s & 127;       // 2KB group 0..7 (16 j-cols each)
            int jl = (g << 4) + (u & 15);
            int p  = (u >> 4) ^ (u & 7);
            spo[i] = jl * DIM + p * 16;
        }
    }
    const unsigned char* tb = yh8 + (size_t)jbase * DIM;
    const int Klane = col * 16 + (((q << 1) ^ (col & 7)) << 8);

    float minv[16];
    #pragma unroll
    for (int i = 0; i < 16; ++i) minv[i] = __builtin_inff();

#define STAGE(BUF, TOFF)                                                                     \
    { _Pragma("unroll")                                                                      \
      for (int i_ = 0; i_ < 2; ++i_) {                                                       \
          __builtin_amdgcn_global_load_lds(                                                  \
              (const __attribute__((address_space(1))) void*)(tb + spo[i_] + (TOFF)),        \
              (__attribute__((address_space(3))) void*)(&Bs[0][0] + (BUF) * 16384 + i_ * 8192 + w * 1024), \
              16, 0, 0);                                                                     \
      } }

    // depth-3 prologue: stages for steps 0,1,2 (buffers 0,1,2); 6 loads in flight/wave
    STAGE(0, 0)                    // jt0 kc0
    STAGE(1, 128)                  // jt0 kc1
    STAGE(2, 256)                  // jt0 kc2

    for (int jt = 0; jt < 16; ++jt) {
        floatx4 acc[4][2];
        #pragma unroll
        for (int mt = 0; mt < 4; ++mt) {
            acc[mt][0] = (floatx4){0.f, 0.f, 0.f, 0.f};
            acc[mt][1] = (floatx4){0.f, 0.f, 0.f, 0.f};
        }
        #pragma unroll
        for (int kc = 0; kc < 4; ++kc) {
            // stage step s+3 into buffer (s+3)&7, s = jt*4+kc. Tail wraps jt' to 0:
            // junk stages read L2-HOT addresses into not-yet-read buffers (no HBM junk).
            const int jtp  = (jt + ((kc + 3) >> 2)) & 15;
            const int toff = jtp * (128 * DIM) + (((kc + 3) & 3) << 7);
            STAGE((jt * 4 + kc + 3) & 7, toff)
            asm volatile("s_waitcnt vmcnt(6)" ::: "memory");  // own stage-s loads landed
            __builtin_amdgcn_s_barrier();                     // ALL waves' stage-s loads landed
            asm volatile("" ::: "memory");
            const unsigned char* bufb = &Bs[0][0] + ((jt * 4 + kc) & 7) * 16384;
            #pragma unroll
            for (int nt = 0; nt < 2; ++nt) {
                const unsigned char* gb = bufb + (c * 2 + nt) * 2048;
                int4v lo = *(const int4v*)(gb + Klane);
                int4v hi = *(const int4v*)(gb + (Klane ^ 256));
                int8v b;
                b[0] = lo[0]; b[1] = lo[1]; b[2] = lo[2]; b[3] = lo[3];
                b[4] = hi[0]; b[5] = hi[1]; b[6] = hi[2]; b[7] = hi[3];
                __builtin_amdgcn_s_setprio(1);
                #pragma unroll
                for (int mt = 0; mt < 4; ++mt)
                    acc[mt][nt] = __builtin_amdgcn_mfma_scale_f32_16x16x128_f8f6f4(
                        afr[mt][kc], b, acc[mt][nt], 0, 0, 0, 127, 0, 127);
                __builtin_amdgcn_s_setprio(0);
            }
        }
        // fold y_sq (from LDS), running min over j (x_sq added later; sqrt monotone)
        #pragma unroll
        for (int nt = 0; nt < 2; ++nt) {
            float qv = ysq_s[jt * 128 + c * 32 + nt * 16 + col];
            #pragma unroll
            for (int mt = 0; mt < 4; ++mt)
                #pragma unroll
                for (int r = 0; r < 4; ++r)
                    minv[mt * 4 + r] = fminf(minv[mt * 4 + r], qv - 2.f * acc[mt][nt][r]);
        }
    }
#undef STAGE

    // reduce over the 16 col-lanes (C-layout: col = lane&15, row = q*4+r)
    #pragma unroll
    for (int i = 0; i < 16; ++i) {
        float v = minv[i];
        v = fminf(v, __shfl_xor(v, 1, 64));
        v = fminf(v, __shfl_xor(v, 2, 64));
        v = fminf(v, __shfl_xor(v, 4, 64));
        v = fminf(v, __shfl_xor(v, 8, 64));
        minv[i] = v;
    }
    if (col == 0) {
        #pragma unroll
        for (int mt = 0; mt < 4; ++mt)
            #pragma unroll
            for (int r = 0; r < 4; ++r)
                red[c][h * 64 + mt * 16 + q * 4 + r] = minv[mt * 4 + r];
    }
    __syncthreads();   // also drains the tail junk stages before wave exit
    if (t < 128)
        part[(size_t)(i0 + t) * JS + js] =
            fminf(fminf(red[0][t], red[1][t]), fminf(red[2][t], red[3][t]));
}

// ---------------- 3a. per-row approx value + global max ----------------
__global__ __launch_bounds__(1024) void maxred_kernel(const float* __restrict__ part,
                                                      const float* __restrict__ x_sq,
                                                      float* __restrict__ aval,
                                                      unsigned int* __restrict__ gmax_bits) {
    __shared__ float sm[1024];
    int t = threadIdx.x;
    int row = blockIdx.x * 1024 + t;
    float m = part[(size_t)row * JS];
    #pragma unroll
    for (int c = 1; c < JS; ++c) m = fminf(m, part[(size_t)row * JS + c]);
    float v = sqrtf(fmaxf(x_sq[row] + m, 0.f));
    aval[row] = v;
    sm[t] = v;
    __syncthreads();
    for (int s = 512; s > 0; s >>= 1) {
        if (t < s) sm[t] = fmaxf(sm[t], sm[t + s]);
        __syncthreads();
    }
    if (t == 0) atomicMax(gmax_bits, __float_as_uint(sm[0]));  // v>=0: uint order == float order
}

// ---------------- 3b. select candidates within DELTA of max ----------------
__global__ __launch_bounds__(1024) void select_kernel(const float* __restrict__ aval,
                                                      const unsigned int* __restrict__ gmax_bits,
                                                      unsigned int* __restrict__ cnt,
                                                      int* __restrict__ cand) {
    int row = blockIdx.x * 1024 + threadIdx.x;
    float gmax = __uint_as_float(*gmax_bits);
    if (aval[row] >= gmax - DELTA) {
        unsigned s = atomicAdd(cnt, 1u);
        if (s < KCAND) cand[s] = row;
    }
}

// ---------------- 4. exact fp32 rescore of candidates vs all centers ----------------
#define TIr 64
#define LDA 68
#define LDB 132
__global__ __launch_bounds__(256) void rescore_kernel(const float* __restrict__ x, const float* __restrict__ y,
                                                      const float* __restrict__ y_sq,
                                                      const int* __restrict__ cand,
                                                      const unsigned int* __restrict__ cnt,
                                                      float* __restrict__ part2) {
    __shared__ __align__(16) float As[32 * LDA];
    __shared__ __align__(16) float Bs[32 * LDB];
    __shared__ float red[TIr][17];

    int t = threadIdx.x;
    int tx = t & 15, ty = t >> 4;
    int i0 = blockIdx.x * TIr;       // candidate slot base
    int j0 = blockIdx.y * 128;       // center base

    if ((unsigned)i0 >= *cnt) return;   // uniform early-exit: unused candidate blocks

    float acc[4][8];
    #pragma unroll
    for (int c = 0; c < 4; ++c)
        #pragma unroll
        for (int d = 0; d < 8; ++d) acc[c][d] = 0.f;

    int srow = t >> 3;
    int skq = (t & 7) * 4;
    int grow0 = cand[i0 + srow];
    int grow1 = cand[i0 + 32 + srow];

    for (int kc = 0; kc < DIM; kc += 32) {
        {
            float4 v = *(const float4*)(x + (size_t)grow0 * DIM + kc + skq);
            As[(skq + 0) * LDA + srow] = v.x;
            As[(skq + 1) * LDA + srow] = v.y;
            As[(skq + 2) * LDA + srow] = v.z;
            As[(skq + 3) * LDA + srow] = v.w;
            v = *(const float4*)(x + (size_t)grow1 * DIM + kc + skq);
            As[(skq + 0) * LDA + 32 + srow] = v.x;
            As[(skq + 1) * LDA + 32 + srow] = v.y;
            As[(skq + 2) * LDA + 32 + srow] = v.z;
            As[(skq + 3) * LDA + 32 + srow] = v.w;
        }
        #pragma unroll
        for (int it = 0; it < 4; ++it) {
            int row = it * 32 + srow;
            float4 v = *(const float4*)(y + (size_t)(j0 + row) * DIM + kc + skq);
            Bs[(skq + 0) * LDB + row] = v.x;
            Bs[(skq + 1) * LDB + row] = v.y;
            Bs[(skq + 2) * LDB + row] = v.z;
            Bs[(skq + 3) * LDB + row] = v.w;
        }
        __syncthreads();
        #pragma unroll 8
        for (int k = 0; k < 32; ++k) {
            float4 a  = *(const float4*)&As[k * LDA + ty * 4];
            float4 b0 = *(const float4*)&Bs[k * LDB + tx * 8];
            float4 b1 = *(const float4*)&Bs[k * LDB + tx * 8 + 4];
            float av[4] = {a.x, a.y, a.z, a.w};
            float bv[8] = {b0.x, b0.y, b0.z, b0.w, b1.x, b1.y, b1.z, b1.w};
            #pragma unroll
            for (int c = 0; c < 4; ++c)
                #pragma unroll
                for (int d = 0; d < 8; ++d)
                    acc[c][d] = fmaf(av[c], bv[d], acc[c][d]);
        }
        __syncthreads();
    }

    float4 q0 = *(const float4*)(y_sq + j0 + tx * 8);
    float4 q1 = *(const float4*)(y_sq + j0 + tx * 8 + 4);
    float qv[8] = {q0.x, q0.y, q0.z, q0.w, q1.x, q1.y, q1.z, q1.w};
    float mv[4] = {__builtin_inff(), __builtin_inff(), __builtin_inff(), __builtin_inff()};
    #pragma unroll
    for (int c = 0; c < 4; ++c)
        #pragma unroll
        for (int d = 0; d < 8; ++d)
            mv[c] = fminf(mv[c], qv[d] - 2.f * acc[c][d]);
    #pragma unroll
    for (int c = 0; c < 4; ++c) red[ty * 4 + c][tx] = mv[c];
    __syncthreads();
    if (t < TIr) {
        float m = red[t][0];
        #pragma unroll
        for (int xx = 1; xx < 16; ++xx) m = fminf(m, red[t][xx]);
        part2[(size_t)(i0 + t) * 128 + blockIdx.y] = m;
    }
}

// ---------------- 5. final: exact min per candidate, argmax with index tie-break ----------------
__global__ __launch_bounds__(256) void final2_kernel(const float* __restrict__ part2,
                                                     const float* __restrict__ x_sq,
                                                     const int* __restrict__ cand,
                                                     const unsigned int* __restrict__ cnt,
                                                     float* __restrict__ out) {
    __shared__ float sv[256];
    __shared__ int si[256];
    int t = threadIdx.x;
    const float4* p4 = (const float4*)(part2 + (size_t)t * 128);
    float m = __builtin_inff();
    for (int c = 0; c < 32; ++c) {
        float4 v = p4[c];
        m = fminf(m, fminf(fminf(v.x, v.y), fminf(v.z, v.w)));
    }
    unsigned n = *cnt;
    if (n > KCAND) n = KCAND;
    int row = cand[t];
    float v = (t < (int)n) ? sqrtf(fmaxf(x_sq[row] + m, 0.f)) : -__builtin_inff();
    sv[t] = v; si[t] = row;
    __syncthreads();
    for (int s = 128; s > 0; s >>= 1) {
        if (t < s) {
            float v2 = sv[t + s]; int i2 = si[t + s];
            if (v2 > sv[t] || (v2 == sv[t] && i2 < si[t])) { sv[t] = v2; si[t] = i2; }
        }
        __syncthreads();
    }
    if (t == 0) { out[0] = sv[0]; out[1] = (float)si[0]; }
}

extern "C" void kernel_launch(void* const* d_in, const int* in_sizes, int n_in,
                              void* d_out, int out_size, void* d_ws, size_t ws_size,
                              hipStream_t stream) {
    const float* x = (const float*)d_in[0];
    const float* y = (const float*)d_in[1];
    float* out = (float*)d_out;

    char* w = (char*)d_ws;
    unsigned char* xh8 = (unsigned char*)w;                           // 8 MB
    unsigned char* yh8 = (unsigned char*)(w + (size_t)8388608);       // 8 MB
    float* x_sq = (float*)(w + (size_t)16777216);                     // N
    float* y_sq = x_sq + N_ROWS;                                      // M
    float* part = y_sq + M_ROWS;                                      // N*JS
    float* aval = part + (size_t)N_ROWS * JS;                         // N
    float* part2 = aval + N_ROWS;                                     // KCAND*128
    int* cand = (int*)(part2 + KCAND * 128);                          // KCAND
    unsigned int* gmax_bits = (unsigned int*)(cand + KCAND);
    unsigned int* cnt = gmax_bits + 1;

    convert_kernel<<<(N_ROWS + M_ROWS) / 4, 256, 0, stream>>>(x, y, xh8, yh8, x_sq, y_sq, gmax_bits, cnt, cand);
    pass1_kernel<<<1024, 512, 0, stream>>>(xh8, yh8, y_sq, part);
    maxred_kernel<<<N_ROWS / 1024, 1024, 0, stream>>>(part, x_sq, aval, gmax_bits);
    select_kernel<<<N_ROWS / 1024, 1024, 0, stream>>>(aval, gmax_bits, cnt, cand);
    dim3 g2(KCAND / TIr, M_ROWS / 128);
    rescore_kernel<<<g2, 256, 0, stream>>>(x, y, y_sq, cand, cnt, part2);
    final2_kernel<<<1, 256, 0, stream>>>(part2, x_sq, cand, cnt, out);
}

// Round 6
// 269.812 us; speedup vs baseline: 1.2263x; 1.0861x over previous
//
#include <hip/hip_runtime.h>
#include <hip/hip_fp8.h>
#include <math.h>

#define N_ROWS 16384
#define M_ROWS 16384
#define DIM    512
#define JS     8        // j-splits in pass1 (one per XCD)
#define KCAND  256      // max rescore candidates
#define DELTA  0.40f    // selection margin (fp8 dist err sigma ~0.03 -> 13 sigma)

typedef __attribute__((ext_vector_type(8))) int   int8v;
typedef __attribute__((ext_vector_type(4))) int   int4v;
typedef __attribute__((ext_vector_type(4))) float floatx4;

// ---------------- 1. convert fp32 -> fp8 e4m3, exact row norms, init control ----------------
__global__ __launch_bounds__(256) void convert_kernel(const float* __restrict__ x, const float* __restrict__ y,
                                                      unsigned char* __restrict__ xh8, unsigned char* __restrict__ yh8,
                                                      float* __restrict__ x_sq, float* __restrict__ y_sq,
                                                      unsigned int* __restrict__ gmax_bits,
                                                      unsigned int* __restrict__ cnt, int* __restrict__ cand) {
    if (blockIdx.x == 0) {
        if (threadIdx.x < KCAND) cand[threadIdx.x] = 0;
        if (threadIdx.x == 0) { *gmax_bits = 0u; *cnt = 0u; }
    }
    int wave = threadIdx.x >> 6, lane = threadIdx.x & 63;
    int row = blockIdx.x * 4 + wave;
    const float* src; unsigned char* dst8; float* dsq; int r;
    if (row < N_ROWS) { r = row;          src = x; dst8 = xh8; dsq = x_sq; }
    else              { r = row - N_ROWS; src = y; dst8 = yh8; dsq = y_sq; }
    const float4* s4 = (const float4*)(src + (size_t)r * DIM);
    float4 a = s4[lane * 2];
    float4 b = s4[lane * 2 + 1];
    float v[8] = {a.x, a.y, a.z, a.w, b.x, b.y, b.z, b.w};
    union { unsigned char b[8]; uint2 u2; } pk;
    float s = 0.f;
    #pragma unroll
    for (int i = 0; i < 8; ++i) {
        s += v[i] * v[i];
        __hip_fp8_e4m3 q(v[i]);
        pk.b[i] = (unsigned char)q.__x;
    }
    *(uint2*)(dst8 + (size_t)r * DIM + lane * 8) = pk.u2;
    #pragma unroll
    for (int off = 32; off > 0; off >>= 1) s += __shfl_down(s, off, 64);
    if (lane == 0) dsq[r] = s;
}

// ---------------- 2. pass1: MX-fp8 MFMA (unit scales), min_j(y_sq[j] - 2 x.y) ----------------
// 256 threads / 4 waves, LDS 73KB -> 2 blocks/CU = 2 waves/SIMD; 3-4 w/SIMD is LDS-impossible,
// so the allocator's reg cap is 256 (unified) and afr[4][4]=128 VGPR FITS without eviction
// (rounds 3/5 failed because their configs made a 128-reg occupancy bracket attainable).
// Wave (h,c) owns 64 rows x 64 cols: B-read amplification 2x (round 2 was 8x, its limiter).
// Round-2-proven staging: shared cooperative, 4 bufs, depth-2, ONE s_barrier + vmcnt(8)/step.
__global__ __launch_bounds__(256, 2) void pass1_kernel(const unsigned char* __restrict__ xh8,
                                                       const unsigned char* __restrict__ yh8,
                                                       const float* __restrict__ y_sq,
                                                       float* __restrict__ part) {
    __shared__ __align__(16) unsigned char Bs[4][16384];   // 4 x (128 j x 128 kB) buffers
    __shared__ __align__(16) float ysq_s[M_ROWS / JS];     // this block's y_sq slice (8 KB)
    __shared__ float red[2][128];

    const int t = threadIdx.x;
    const int w = t >> 6, lane = t & 63;
    const int col = lane & 15, q = lane >> 4;
    const int h = w >> 1, c = w & 1;        // row-half (64 rows), col-half (64 cols)

    // XCD swizzle (1024 blocks % 8 == 0): XCD x owns jsplit x -> its 1MB y-slice stays in L2
    const int bid = blockIdx.x;
    const int wg = (bid & 7) * 128 + (bid >> 3);
    const int js = wg >> 7;                 // 0..7
    const int i0 = (wg & 127) * 128;        // x-row base
    const int jbase = js * (M_ROWS / JS);

    // ---- prologue: y_sq slice -> LDS ----
    {
        const float4* ys4 = (const float4*)(y_sq + jbase);
        float4 v0 = ys4[t * 2];
        float4 v1 = ys4[t * 2 + 1];
        *(float4*)&ysq_s[t * 8]     = v0;
        *(float4*)&ysq_s[t * 8 + 4] = v1;
    }

    // ---- A tile (128 rows x 512 B) -> Bs (all 64 KB) with phi-chunk swizzle ----
    // physical 16B slot (r, kq, p) holds logical chunk cl = p ^ (r&7) of row r's kq-th 128B
    {
        const unsigned char* gs = xh8 + (size_t)i0 * DIM;
        unsigned char* ls = (unsigned char*)Bs;
        #pragma unroll
        for (int it = 0; it < 16; ++it) {
            int s  = it * 256 + t;          // 16B slot 0..4095
            int r  = s >> 5;                // A row 0..127
            int u  = s & 31;
            int kq = u >> 3;                // 128B k-chunk 0..3
            int cl = (u & 7) ^ (r & 7);     // logical chunk for this physical slot
            __builtin_amdgcn_global_load_lds(
                (const __attribute__((address_space(1))) void*)(gs + r * 512 + kq * 128 + cl * 16),
                (__attribute__((address_space(3))) void*)(ls + it * 4096 + w * 1024),
                16, 0, 0);
        }
    }
    __syncthreads();   // A staged (drains vmcnt), ysq_s visible

    // ---- A fragments -> registers: wave holds rows i0 + h*64 .. +63, all K (16 frags) ----
    // f8f6f4 16x16x128 A-layout: lane(q,col) holds row=col, k bytes [q*32, q*32+32)
    int8v afr[4][4];
    {
        const unsigned char* ab = (const unsigned char*)Bs;
        #pragma unroll
        for (int mt = 0; mt < 4; ++mt) {
            int rr = h * 64 + mt * 16 + col;
            #pragma unroll
            for (int kc = 0; kc < 4; ++kc) {
                int base = rr * 512 + kc * 128 + (((q << 1) ^ (rr & 7)) << 4);
                int4v a0 = *(const int4v*)(ab + base);
                int4v a1 = *(const int4v*)(ab + (base ^ 16));
                int8v f;
                f[0] = a0[0]; f[1] = a0[1]; f[2] = a0[2]; f[3] = a0[3];
                f[4] = a1[0]; f[5] = a1[1]; f[6] = a1[2]; f[7] = a1[3];
                afr[mt][kc] = f;
            }
        }
    }
    __syncthreads();   // all afr reads done before B pipeline overwrites Bs

    // ---- B staging offsets (phi-layout: slot u = j4 + 16*(p ^ (j4&7)) within 2KB group) ----
    int spo[4];
    {
        #pragma unroll
        for (int i = 0; i < 4; ++i) {
            int s  = w * 256 + i * 64 + lane;   // 16B slot this lane fills
            int g  = s >> 7, u = s & 127;
            int jl = (g << 4) + (u & 15);
            int p  = (u >> 4) ^ (u & 7);
            spo[i] = jl * DIM + p * 16;
        }
    }
    const unsigned char* tb = yh8 + (size_t)jbase * DIM;
    const int Klane = col * 16 + (((q << 1) ^ (col & 7)) << 8);

    float minv[16];
    #pragma unroll
    for (int i = 0; i < 16; ++i) minv[i] = __builtin_inff();

#define STAGE(BUF, TOFF)                                                                     \
    { _Pragma("unroll")                                                                      \
      for (int i_ = 0; i_ < 4; ++i_) {                                                       \
          __builtin_amdgcn_global_load_lds(                                                  \
              (const __attribute__((address_space(1))) void*)(tb + spo[i_] + (TOFF)),        \
              (__attribute__((address_space(3))) void*)(&Bs[BUF][w * 4096 + i_ * 1024]),     \
              16, 0, 0);                                                                     \
      } }

    STAGE(0, 0)       // step 0: jt 0, kcol 0
    STAGE(1, 128)     // step 1: jt 0, kcol 128

    for (int jt = 0; jt < 16; ++jt) {
        floatx4 acc[4][4];
        #pragma unroll
        for (int mt = 0; mt < 4; ++mt)
            #pragma unroll
            for (int nt = 0; nt < 4; ++nt) acc[mt][nt] = (floatx4){0.f, 0.f, 0.f, 0.f};
        #pragma unroll
        for (int kc = 0; kc < 4; ++kc) {
            // stage step s+2 into buffer (kc+2)&3. Tail (jt=15, kc>=2) wraps jt' to 0:
            // junk stages read L2-HOT addresses into no-longer-read buffers (no HBM junk).
            const int jtp  = (jt + (kc >> 1)) & 15;
            const int toff = jtp * (128 * DIM) + (((kc + 2) & 3) << 7);
            STAGE((kc + 2) & 3, toff)
            asm volatile("s_waitcnt vmcnt(8)" ::: "memory");  // own stage landed; 8 newer in flight
            __builtin_amdgcn_s_barrier();                     // all waves' stage-s loads landed
            asm volatile("" ::: "memory");
            #pragma unroll
            for (int nt = 0; nt < 4; ++nt) {
                const unsigned char* gb = &Bs[kc][(c * 4 + nt) * 2048];
                int4v lo = *(const int4v*)(gb + Klane);
                int4v hi = *(const int4v*)(gb + (Klane ^ 256));
                int8v b;
                b[0] = lo[0]; b[1] = lo[1]; b[2] = lo[2]; b[3] = lo[3];
                b[4] = hi[0]; b[5] = hi[1]; b[6] = hi[2]; b[7] = hi[3];
                __builtin_amdgcn_s_setprio(1);
                #pragma unroll
                for (int mt = 0; mt < 4; ++mt)
                    acc[mt][nt] = __builtin_amdgcn_mfma_scale_f32_16x16x128_f8f6f4(
                        afr[mt][kc], b, acc[mt][nt], 0, 0, 0, 127, 0, 127);
                __builtin_amdgcn_s_setprio(0);
            }
        }
        // fold y_sq (from LDS), running min over j (x_sq added later; sqrt monotone)
        #pragma unroll
        for (int nt = 0; nt < 4; ++nt) {
            float qv = ysq_s[jt * 128 + c * 64 + nt * 16 + col];
            #pragma unroll
            for (int mt = 0; mt < 4; ++mt)
                #pragma unroll
                for (int r = 0; r < 4; ++r)
                    minv[mt * 4 + r] = fminf(minv[mt * 4 + r], qv - 2.f * acc[mt][nt][r]);
        }
    }
#undef STAGE

    // reduce over the 16 col-lanes (C-layout: col = lane&15, row = q*4+r)
    #pragma unroll
    for (int i = 0; i < 16; ++i) {
        float v = minv[i];
        v = fminf(v, __shfl_xor(v, 1, 64));
        v = fminf(v, __shfl_xor(v, 2, 64));
        v = fminf(v, __shfl_xor(v, 4, 64));
        v = fminf(v, __shfl_xor(v, 8, 64));
        minv[i] = v;
    }
    if (col == 0) {
        #pragma unroll
        for (int mt = 0; mt < 4; ++mt)
            #pragma unroll
            for (int r = 0; r < 4; ++r)
                red[c][h * 64 + mt * 16 + q * 4 + r] = minv[mt * 4 + r];
    }
    __syncthreads();   // also drains the tail junk stages before wave exit
    if (t < 128)
        part[(size_t)(i0 + t) * JS + js] = fminf(red[0][t], red[1][t]);
}

// ---------------- 3a. per-row approx value + global max ----------------
__global__ __launch_bounds__(1024) void maxred_kernel(const float* __restrict__ part,
                                                      const float* __restrict__ x_sq,
                                                      float* __restrict__ aval,
                                                      unsigned int* __restrict__ gmax_bits) {
    __shared__ float sm[1024];
    int t = threadIdx.x;
    int row = blockIdx.x * 1024 + t;
    float m = part[(size_t)row * JS];
    #pragma unroll
    for (int c = 1; c < JS; ++c) m = fminf(m, part[(size_t)row * JS + c]);
    float v = sqrtf(fmaxf(x_sq[row] + m, 0.f));
    aval[row] = v;
    sm[t] = v;
    __syncthreads();
    for (int s = 512; s > 0; s >>= 1) {
        if (t < s) sm[t] = fmaxf(sm[t], sm[t + s]);
        __syncthreads();
    }
    if (t == 0) atomicMax(gmax_bits, __float_as_uint(sm[0]));  // v>=0: uint order == float order
}

// ---------------- 3b. select candidates within DELTA of max ----------------
__global__ __launch_bounds__(1024) void select_kernel(const float* __restrict__ aval,
                                                      const unsigned int* __restrict__ gmax_bits,
                                                      unsigned int* __restrict__ cnt,
                                                      int* __restrict__ cand) {
    int row = blockIdx.x * 1024 + threadIdx.x;
    float gmax = __uint_as_float(*gmax_bits);
    if (aval[row] >= gmax - DELTA) {
        unsigned s = atomicAdd(cnt, 1u);
        if (s < KCAND) cand[s] = row;
    }
}

// ---------------- 4. exact fp32 rescore of candidates vs all centers ----------------
#define TIr 64
#define LDA 68
#define LDB 132
__global__ __launch_bounds__(256) void rescore_kernel(const float* __restrict__ x, const float* __restrict__ y,
                                                      const float* __restrict__ y_sq,
                                                      const int* __restrict__ cand,
                                                      const unsigned int* __restrict__ cnt,
                                                      float* __restrict__ part2) {
    __shared__ __align__(16) float As[32 * LDA];
    __shared__ __align__(16) float Bs[32 * LDB];
    __shared__ float red[TIr][17];

    int t = threadIdx.x;
    int tx = t & 15, ty = t >> 4;
    int i0 = blockIdx.x * TIr;       // candidate slot base
    int j0 = blockIdx.y * 128;       // center base

    if ((unsigned)i0 >= *cnt) return;   // uniform early-exit: unused candidate blocks

    float acc[4][8];
    #pragma unroll
    for (int c = 0; c < 4; ++c)
        #pragma unroll
        for (int d = 0; d < 8; ++d) acc[c][d] = 0.f;

    int srow = t >> 3;
    int skq = (t & 7) * 4;
    int grow0 = cand[i0 + srow];
    int grow1 = cand[i0 + 32 + srow];

    for (int kc = 0; kc < DIM; kc += 32) {
        {
            float4 v = *(const float4*)(x + (size_t)grow0 * DIM + kc + skq);
            As[(skq + 0) * LDA + srow] = v.x;
            As[(skq + 1) * LDA + srow] = v.y;
            As[(skq + 2) * LDA + srow] = v.z;
            As[(skq + 3) * LDA + srow] = v.w;
            v = *(const float4*)(x + (size_t)grow1 * DIM + kc + skq);
            As[(skq + 0) * LDA + 32 + srow] = v.x;
            As[(skq + 1) * LDA + 32 + srow] = v.y;
            As[(skq + 2) * LDA + 32 + srow] = v.z;
            As[(skq + 3) * LDA + 32 + srow] = v.w;
        }
        #pragma unroll
        for (int it = 0; it < 4; ++it) {
            int row = it * 32 + srow;
            float4 v = *(const float4*)(y + (size_t)(j0 + row) * DIM + kc + skq);
            Bs[(skq + 0) * LDB + row] = v.x;
            Bs[(skq + 1) * LDB + row] = v.y;
            Bs[(skq + 2) * LDB + row] = v.z;
            Bs[(skq + 3) * LDB + row] = v.w;
        }
        __syncthreads();
        #pragma unroll 8
        for (int k = 0; k < 32; ++k) {
            float4 a  = *(const float4*)&As[k * LDA + ty * 4];
            float4 b0 = *(const float4*)&Bs[k * LDB + tx * 8];
            float4 b1 = *(const float4*)&Bs[k * LDB + tx * 8 + 4];
            float av[4] = {a.x, a.y, a.z, a.w};
            float bv[8] = {b0.x, b0.y, b0.z, b0.w, b1.x, b1.y, b1.z, b1.w};
            #pragma unroll
            for (int c = 0; c < 4; ++c)
                #pragma unroll
                for (int d = 0; d < 8; ++d)
                    acc[c][d] = fmaf(av[c], bv[d], acc[c][d]);
        }
        __syncthreads();
    }

    float4 q0 = *(const float4*)(y_sq + j0 + tx * 8);
    float4 q1 = *(const float4*)(y_sq + j0 + tx * 8 + 4);
    float qv[8] = {q0.x, q0.y, q0.z, q0.w, q1.x, q1.y, q1.z, q1.w};
    float mv[4] = {__builtin_inff(), __builtin_inff(), __builtin_inff(), __builtin_inff()};
    #pragma unroll
    for (int c = 0; c < 4; ++c)
        #pragma unroll
        for (int d = 0; d < 8; ++d)
            mv[c] = fminf(mv[c], qv[d] - 2.f * acc[c][d]);
    #pragma unroll
    for (int c = 0; c < 4; ++c) red[ty * 4 + c][tx] = mv[c];
    __syncthreads();
    if (t < TIr) {
        float m = red[t][0];
        #pragma unroll
        for (int xx = 1; xx < 16; ++xx) m = fminf(m, red[t][xx]);
        part2[(size_t)(i0 + t) * 128 + blockIdx.y] = m;
    }
}

// ---------------- 5. final: exact min per candidate, argmax with index tie-break ----------------
__global__ __launch_bounds__(256) void final2_kernel(const float* __restrict__ part2,
                                                     const float* __restrict__ x_sq,
                                                     const int* __restrict__ cand,
                                                     const unsigned int* __restrict__ cnt,
                                                     float* __restrict__ out) {
    __shared__ float sv[256];
    __shared__ int si[256];
    int t = threadIdx.x;
    const float4* p4 = (const float4*)(part2 + (size_t)t * 128);
    float m = __builtin_inff();
    for (int c = 0; c < 32; ++c) {
        float4 v = p4[c];
        m = fminf(m, fminf(fminf(v.x, v.y), fminf(v.z, v.w)));
    }
    unsigned n = *cnt;
    if (n > KCAND) n = KCAND;
    int row = cand[t];
    float v = (t < (int)n) ? sqrtf(fmaxf(x_sq[row] + m, 0.f)) : -__builtin_inff();
    sv[t] = v; si[t] = row;
    __syncthreads();
    for (int s = 128; s > 0; s >>= 1) {
        if (t < s) {
            float v2 = sv[t + s]; int i2 = si[t + s];
            if (v2 > sv[t] || (v2 == sv[t] && i2 < si[t])) { sv[t] = v2; si[t] = i2; }
        }
        __syncthreads();
    }
    if (t == 0) { out[0] = sv[0]; out[1] = (float)si[0]; }
}

extern "C" void kernel_launch(void* const* d_in, const int* in_sizes, int n_in,
                              void* d_out, int out_size, void* d_ws, size_t ws_size,
                              hipStream_t stream) {
    const float* x = (const float*)d_in[0];
    const float* y = (const float*)d_in[1];
    float* out = (float*)d_out;

    char* w = (char*)d_ws;
    unsigned char* xh8 = (unsigned char*)w;                           // 8 MB
    unsigned char* yh8 = (unsigned char*)(w + (size_t)8388608);       // 8 MB
    float* x_sq = (float*)(w + (size_t)16777216);                     // N
    float* y_sq = x_sq + N_ROWS;                                      // M
    float* part = y_sq + M_ROWS;                                      // N*JS
    float* aval = part + (size_t)N_ROWS * JS;                         // N
    float* part2 = aval + N_ROWS;                                     // KCAND*128
    int* cand = (int*)(part2 + KCAND * 128);                          // KCAND
    unsigned int* gmax_bits = (unsigned int*)(cand + KCAND);
    unsigned int* cnt = gmax_bits + 1;

    convert_kernel<<<(N_ROWS + M_ROWS) / 4, 256, 0, stream>>>(x, y, xh8, yh8, x_sq, y_sq, gmax_bits, cnt, cand);
    pass1_kernel<<<1024, 256, 0, stream>>>(xh8, yh8, y_sq, part);
    maxred_kernel<<<N_ROWS / 1024, 1024, 0, stream>>>(part, x_sq, aval, gmax_bits);
    select_kernel<<<N_ROWS / 1024, 1024, 0, stream>>>(aval, gmax_bits, cnt, cand);
    dim3 g2(KCAND / TIr, M_ROWS / 128);
    rescore_kernel<<<g2, 256, 0, stream>>>(x, y, y_sq, cand, cnt, part2);
    final2_kernel<<<1, 256, 0, stream>>>(part2, x_sq, cand, cnt, out);
}